// Round 8
// baseline (682.699 us; speedup 1.0000x reference)
//
#include <hip/hip_runtime.h>
#include <hip/hip_cooperative_groups.h>

namespace cg = cooperative_groups;

// Capsule routing, single persistent cooperative kernel, all fp32, NO global atomics.
// B=256, K_IN=8, C=1152, J=10, D=16, 4 iters.
// m = k*1152 + c (M=9216), n = j*16 + d (N=160).
// 256 blocks x 512 threads; each block = two independent 256-thread halves, each
// half running one R7-style sub-block. 11 grid.syncs replace 12 kernel boundaries.
// All cross-block reduction via plain-store split buffers (s_part / agg_part).

#define C_IN  1152
#define J_U   10
#define M_DIM 9216
#define N_DIM 160
#define B_SZ  256

// ---- ws layout (float offsets) ----
#define OFF_XT   0                    // [9216+4 pad rows][256]
#define OFF_WR   2400000              // [9216][160]
#define OFF_SP   3900000              // [128][256][160]
#define OFF_V    9200000              // [256][160]
#define OFF_B0   9250000              // [1152][10]
#define OFF_B1   9270000              // [1152][10]
#define OFF_AG   9290000              // [32][1152][10]

#define HALF_LDS 13000                // floats per 256-thread half

__global__ __launch_bounds__(512, 2) void caps_all(const float* __restrict__ x,
                                                   const float* __restrict__ W,
                                                   float* __restrict__ out,
                                                   float* __restrict__ ws) {
    cg::grid_group grid = cg::this_grid();
    __shared__ alignas(16) float smf[2 * HALF_LDS];   // 104 KB
    const int bid = blockIdx.x, t = threadIdx.x;
    const int half = t >> 8, tl = t & 255;
    float* base = smf + half * HALF_LDS;
    float* Xt   = ws + OFF_XT;
    float* Wr   = ws + OFF_WR;
    float* sp   = ws + OFF_SP;
    float* vbuf = ws + OFF_V;
    float* bij0 = ws + OFF_B0;
    float* bij1 = ws + OFF_B1;
    float* aggp = ws + OFF_AG;

    // ======================= prep =======================
    {
        // x -> Xt, 64x64 LDS tile transpose; one tile per half, grid-strided.
        for (int tile = bid * 2 + half; tile < 576; tile += 512) {
            const int m0 = (tile % 144) * 64, b0 = (tile / 144) * 64;
            {
                const int b_l = tl >> 2, q = tl & 3;
                const float* xp = x + (size_t)(b0 + b_l) * M_DIM + m0 + q * 16;
#pragma unroll
                for (int u = 0; u < 4; ++u) {
                    const float4 v4 = *reinterpret_cast<const float4*>(xp + 4 * u);
                    base[(q * 16 + 4 * u + 0) * 65 + b_l] = v4.x;
                    base[(q * 16 + 4 * u + 1) * 65 + b_l] = v4.y;
                    base[(q * 16 + 4 * u + 2) * 65 + b_l] = v4.z;
                    base[(q * 16 + 4 * u + 3) * 65 + b_l] = v4.w;
                }
            }
            __syncthreads();
            {
                const int m_l = tl >> 2, q = tl & 3;
                float4* op = reinterpret_cast<float4*>(Xt + (size_t)(m0 + m_l) * B_SZ + b0 + q * 16);
#pragma unroll
                for (int u = 0; u < 4; ++u)
                    op[u] = make_float4(base[m_l * 65 + q * 16 + 4 * u],
                                        base[m_l * 65 + q * 16 + 4 * u + 1],
                                        base[m_l * 65 + q * 16 + 4 * u + 2],
                                        base[m_l * 65 + q * 16 + 4 * u + 3]);
            }
            __syncthreads();
        }
        // Wr[(k*C+c)][n] = W[c][n][k]
        const int g = bid * 512 + t;
        for (int i = g; i < C_IN * J_U * 16 * 2; i += 131072) {
            const int n  = i % N_DIM;
            const int c  = (i / N_DIM) % C_IN;
            const int kh = i / (N_DIM * C_IN);
            const float4 w = *reinterpret_cast<const float4*>(W + (size_t)c * 1280 + n * 8 + kh * 4);
            const float wv[4] = {w.x, w.y, w.z, w.w};
#pragma unroll
            for (int j = 0; j < 4; ++j)
                Wr[(size_t)((kh * 4 + j) * C_IN + c) * N_DIM + n] = wv[j];
        }
        for (int i = g; i < 2 * 11520; i += 131072) {
            bij0[i % 11520 + (i / 11520) * 0] = 0.f;   // i<11520 -> bij0, else bij1
            if (i < 11520) bij0[i] = 0.f; else bij1[i - 11520] = 0.f;
        }
        for (int i = g; i < 32 * 11520; i += 131072) aggp[i] = 0.f;
    }
    grid.sync();

    for (int it = 0; it < 4; ++it) {
        const float* bo = (it & 1) ? bij1 : bij0;
        float*       bn = (it & 1) ? bij0 : bij1;

        // ======================= gemm1 (512 sub-blocks, one per half) =======================
        {
            float* braw = base;
            float* csm  = base + 720;
            float* Ws   = base + 1440;      // 72*160
            const int s = bid * 2 + half;
            const int ch = s >> 2, bq4 = s & 3;
            const int m0 = ch * 72;
            const int c0 = (ch & 15) * 72;

            for (int idx = tl; idx < 720; idx += 256) {
                float v = bo[c0 * J_U + idx];
#pragma unroll
                for (int sl = 0; sl < 32; ++sl) v += aggp[sl * 11520 + c0 * J_U + idx];
                braw[idx] = v;
                bn[c0 * J_U + idx] = v;
            }
            __syncthreads();
            for (int idx = tl; idx < 720; idx += 256) {
                const int r0 = (idx / J_U) * J_U;
                float mx = -1e30f;
#pragma unroll
                for (int j = 0; j < J_U; ++j) mx = fmaxf(mx, braw[r0 + j]);
                float sum = 0.f;
#pragma unroll
                for (int j = 0; j < J_U; ++j) sum += __expf(braw[r0 + j] - mx);
                csm[idx] = __expf(braw[idx] - mx) / sum;
            }
            __syncthreads();
            float4* Ws4 = reinterpret_cast<float4*>(Ws);
            const float4* Wr4 = reinterpret_cast<const float4*>(Wr);
            for (int i = tl; i < 2880; i += 256) {
                const int row = i / 40, q = i - row * 40;
                const float sc = csm[row * J_U + (q >> 2)];
                const float4 w = Wr4[(size_t)(m0 + row) * 40 + q];
                Ws4[i] = make_float4(w.x * sc, w.y * sc, w.z * sc, w.w * sc);
            }
            __syncthreads();
            const int bq = tl & 15, ng = tl >> 4;
            const float* xb = Xt + (size_t)m0 * B_SZ + bq4 * 64 + bq * 4;
            float acc[4][10] = {};
            float4 pf[4];
#pragma unroll
            for (int i = 0; i < 4; ++i)
                pf[i] = *reinterpret_cast<const float4*>(xb + (size_t)i * B_SZ);
#pragma unroll 4
            for (int m = 0; m < 72; ++m) {
                const float4 nxt = *reinterpret_cast<const float4*>(xb + (size_t)(m + 4) * B_SZ);
                const float4 cur = pf[0];
                pf[0] = pf[1]; pf[1] = pf[2]; pf[2] = pf[3]; pf[3] = nxt;
                const float2* wr = reinterpret_cast<const float2*>(Ws + m * N_DIM + ng * J_U);
                const float xv[4] = {cur.x, cur.y, cur.z, cur.w};
#pragma unroll
                for (int jj = 0; jj < 5; ++jj) {
                    const float2 wv = wr[jj];
#pragma unroll
                    for (int i = 0; i < 4; ++i) {
                        acc[i][2 * jj]     += xv[i] * wv.x;
                        acc[i][2 * jj + 1] += xv[i] * wv.y;
                    }
                }
            }
            float* spp = sp + (size_t)ch * 40960 + (size_t)(bq4 * 64 + bq * 4) * N_DIM + ng * J_U;
#pragma unroll
            for (int i = 0; i < 4; ++i) {
                float2* p = reinterpret_cast<float2*>(spp + (size_t)i * N_DIM);
#pragma unroll
                for (int jj = 0; jj < 5; ++jj)
                    p[jj] = make_float2(acc[i][2 * jj], acc[i][2 * jj + 1]);
            }
            __syncthreads();   // both halves done with LDS before next phase reuses it
        }
        grid.sync();

        // ======================= squash (one b per block) =======================
        {
            float* red = smf;          // [320]
            float* sq  = smf + 320;    // [160]
            float* dst = (it < 3) ? vbuf : out;
            const int b = bid;
            if (t < 320) {
                const int n = t % 160, h = t / 160;
                float s = 0.f;
                const float* p = sp + (size_t)h * 64 * 40960 + (size_t)b * N_DIM + n;
#pragma unroll 8
                for (int sl = 0; sl < 64; ++sl) s += p[(size_t)sl * 40960];
                red[t] = s;
            }
            __syncthreads();
            if (t < 160) {
                const float s = red[t] + red[t + 160] + 1e-5f;  // +1e-5 BEFORE magnitudes
                sq[t] = s * s;
                red[t] = s;
            }
            __syncthreads();
            if (t < 160) {
                const int j0 = t & ~15;
                float mag = 0.f;
#pragma unroll
                for (int d = 0; d < 16; ++d) mag += sq[j0 + d];
                dst[(size_t)b * N_DIM + t] = red[t] * (sqrtf(mag) / (1.f + mag));
            }
            __syncthreads();
        }
        if (it >= 3) return;
        grid.sync();

        // ============ gemm2 (576 sub-blocks; bid<32 blocks run 2 passes per half) ============
        {
            float* VG  = base;          // v-panel [64][160] then G-tile [64][164]
            float* agg = base + 10496;  // [640]
            const int npass = (bid < 32) ? 2 : 1;
            for (int pass = 0; pass < npass; ++pass) {
                const int s = bid * 2 + half + pass * 512;
                const int mt = s >> 2, bq = s & 3;
                const int m0 = mt * 64, b0 = bq * 64;

                float4* Vs4 = reinterpret_cast<float4*>(VG);
                const float4* v4 = reinterpret_cast<const float4*>(vbuf);
                for (int i = tl; i < 2560; i += 256) Vs4[i] = v4[(size_t)bq * 2560 + i];
                for (int i = tl; i < 640; i += 256) agg[i] = 0.f;
                __syncthreads();

                const int tm = tl & 15, ng = tl >> 4;
                float acc[4][10] = {};
                const float* xb = x + (size_t)b0 * M_DIM + m0 + tm * 4;
                const float2* Vs2 = reinterpret_cast<const float2*>(VG);
                float4 pf[4];
#pragma unroll
                for (int i = 0; i < 4; ++i)
                    pf[i] = *reinterpret_cast<const float4*>(xb + (size_t)i * M_DIM);
#pragma unroll 4
                for (int b = 0; b < 64; ++b) {
                    const int bf = (b + 4 < 64) ? b + 4 : 63;
                    const float4 nxt = *reinterpret_cast<const float4*>(xb + (size_t)bf * M_DIM);
                    const float4 cur = pf[0];
                    pf[0] = pf[1]; pf[1] = pf[2]; pf[2] = pf[3]; pf[3] = nxt;
                    const float2* vv = Vs2 + b * 80 + ng * 5;
                    const float xv[4] = {cur.x, cur.y, cur.z, cur.w};
#pragma unroll
                    for (int jj = 0; jj < 5; ++jj) {
                        const float2 w = vv[jj];
#pragma unroll
                        for (int i = 0; i < 4; ++i) {
                            acc[i][2 * jj]     += xv[i] * w.x;
                            acc[i][2 * jj + 1] += xv[i] * w.y;
                        }
                    }
                }
                __syncthreads();
#pragma unroll
                for (int i = 0; i < 4; ++i)
#pragma unroll
                    for (int q = 0; q < 10; ++q)
                        VG[(tm * 4 + i) * 164 + ng * 10 + q] = acc[i][q];
                __syncthreads();
                const float4* Wr4 = reinterpret_cast<const float4*>(Wr);
                for (int idx = tl; idx < 2560; idx += 256) {
                    const int row = idx / 40, q = idx - row * 40;
                    const float4 w = Wr4[(size_t)(m0 + row) * 40 + q];
                    const float4 g = *reinterpret_cast<const float4*>(&VG[row * 164 + q * 4]);
                    atomicAdd(&agg[row * J_U + (q >> 2)],
                              w.x * g.x + w.y * g.y + w.z * g.z + w.w * g.w);
                }
                __syncthreads();
                const int k = m0 / C_IN, c0 = m0 - k * C_IN;
                for (int i = tl; i < 640; i += 256)
                    aggp[(size_t)(bq * 8 + k) * 11520 + c0 * J_U + i] = agg[i];
                __syncthreads();
            }
        }
        grid.sync();
    }
}

extern "C" void kernel_launch(void* const* d_in, const int* in_sizes, int n_in,
                              void* d_out, int out_size, void* d_ws, size_t ws_size,
                              hipStream_t stream) {
    const float* x = (const float*)d_in[0];   // (256, 8, 1152) fp32
    const float* W = (const float*)d_in[1];   // (1, 1152, 10, 16, 8) fp32
    float* out = (float*)d_out;               // (256, 10, 16, 1) fp32
    float* ws  = (float*)d_ws;
    void* args[] = {(void*)&x, (void*)&W, (void*)&out, (void*)&ws};
    hipLaunchCooperativeKernel((void*)caps_all, dim3(256), dim3(512), args, 0, stream);
}

// Round 9
// 270.911 us; speedup vs baseline: 2.5200x; 2.5200x over previous
//
#include <hip/hip_runtime.h>

// Capsule routing, factorized, all fp32, multi-kernel (no global atomics, no coop).
// B=256, K_IN=8, C=1152, J=10, D=16, 4 iters.
// m = k*1152 + c (M=9216), n = j*16 + d (N=160).
// Per iter: [gemm1] s_part[ch][b][n] = sum_{m in ch} Xt[m,b]*csm[c,j]*Wr[m,n]
//           (gemm1 prologue: b_ij += sum_32 agg_part; csm = softmax(b_ij); iter0 fast path)
//           [squash] v[b][n] = squash(sum_ch s_part)
//           [gemm2]  G-tile = sum_{b in quarter} x[b,m]*v[b,n] (regs, coalesced x)
//                    then fold with Wr (coalesced, LDS round-trip) -> agg_part[bq*8+k]

#define C_IN  1152
#define J_U   10
#define M_DIM 9216
#define N_DIM 160
#define B_SZ  256

// ---- ws layout (float offsets); ws is 256 MiB so offsets are generous ----
#define OFF_XT   0                    // [9216][256]
#define OFF_WR   2400000              // [9216][160]
#define OFF_SP   3900000              // [128][256][160]
#define OFF_V    9200000              // [256][160]
#define OFF_B0   9250000              // [1152][10]
#define OFF_B1   9270000              // [1152][10]
#define OFF_AG   9290000              // [32][1152][10]

// ================= prep: transpose x -> Xt, build Wr =================
__global__ __launch_bounds__(256) void k_prep(const float* __restrict__ x,
                                              const float* __restrict__ W,
                                              float* __restrict__ ws) {
    const int bid = blockIdx.x, t = threadIdx.x;
    if (bid < 576) {                       // 144 m-tiles x 4 b-tiles, 64x64 transpose
        __shared__ float T[64][65];
        const int m0 = (bid % 144) * 64, b0 = (bid / 144) * 64;
        {
            const int b_l = t >> 2, q = t & 3;
            const float* xp = x + (size_t)(b0 + b_l) * M_DIM + m0 + q * 16;
#pragma unroll
            for (int u = 0; u < 4; ++u) {
                const float4 v = *reinterpret_cast<const float4*>(xp + 4 * u);
                T[q * 16 + 4 * u + 0][b_l] = v.x;
                T[q * 16 + 4 * u + 1][b_l] = v.y;
                T[q * 16 + 4 * u + 2][b_l] = v.z;
                T[q * 16 + 4 * u + 3][b_l] = v.w;
            }
        }
        __syncthreads();
        {
            const int m_l = t >> 2, q = t & 3;
            float* Xt = ws + OFF_XT;
            float4* op = reinterpret_cast<float4*>(Xt + (size_t)(m0 + m_l) * B_SZ + b0 + q * 16);
#pragma unroll
            for (int u = 0; u < 4; ++u)
                op[u] = make_float4(T[m_l][q * 16 + 4 * u], T[m_l][q * 16 + 4 * u + 1],
                                    T[m_l][q * 16 + 4 * u + 2], T[m_l][q * 16 + 4 * u + 3]);
        }
    } else {                               // Wr[(k*C+c)][n] = W[c][n][k]
        const int i = (bid - 576) * 256 + t;    // [0, 368640)
        const int n = i % N_DIM;
        const int c = (i / N_DIM) % C_IN;
        const int kh = i / (N_DIM * C_IN);      // 0..1
        const float4 w = *reinterpret_cast<const float4*>(W + (size_t)c * 1280 + n * 8 + kh * 4);
        float* Wr = ws + OFF_WR;
        const float wv[4] = {w.x, w.y, w.z, w.w};
#pragma unroll
        for (int j = 0; j < 4; ++j)
            Wr[(size_t)((kh * 4 + j) * C_IN + c) * N_DIM + n] = wv[j];
    }
}

// ================= gemm1: 128 chunks(72 m) x 4 b-quarters(64 b) = 512 blocks =======
// 2 blocks/CU. Whole x-slice (72x64 = 18 KB) staged to LDS once -> inner loop is
// pure LDS/VALU, no loop-carried global loads.
__global__ __launch_bounds__(256, 2) void k_gemm1(const float* __restrict__ Xt,
                                                  const float4* __restrict__ Wr4,
                                                  const float* __restrict__ bij_old,
                                                  float* __restrict__ bij_new,
                                                  const float* __restrict__ agg_part,
                                                  float* __restrict__ s_part,
                                                  int first) {
    __shared__ float braw[720];
    __shared__ float csm[720];
    __shared__ float Ws[72 * 160];
    __shared__ alignas(16) float Xs[72 * 64];
    const int ch = blockIdx.x >> 2, bq4 = blockIdx.x & 3;
    const int m0 = ch * 72;
    const int c0 = (ch & 15) * 72;        // chunk sits inside one k-slice (1152/72=16)
    const int t = threadIdx.x;

    if (first) {
        // b_ij == 0: softmax(0) = 1/J exactly; skip the 32-slice agg read.
        for (int idx = t; idx < 720; idx += 256) {
            csm[idx] = 0.1f;
            bij_new[c0 * J_U + idx] = 0.f;
        }
    } else {
        for (int idx = t; idx < 720; idx += 256) {
            float v = bij_old[c0 * J_U + idx];
#pragma unroll
            for (int s = 0; s < 32; ++s) v += agg_part[s * 11520 + c0 * J_U + idx];
            braw[idx] = v;
            bij_new[c0 * J_U + idx] = v;
        }
        __syncthreads();
        for (int idx = t; idx < 720; idx += 256) {    // softmax over j
            const int r0 = (idx / J_U) * J_U;
            float mx = -1e30f;
#pragma unroll
            for (int j = 0; j < J_U; ++j) mx = fmaxf(mx, braw[r0 + j]);
            float sum = 0.f;
#pragma unroll
            for (int j = 0; j < J_U; ++j) sum += __expf(braw[r0 + j] - mx);
            csm[idx] = __expf(braw[idx] - mx) / sum;
        }
    }
    __syncthreads();
    // ---- stage scaled W panel + x panel ----
    float4* Ws4 = reinterpret_cast<float4*>(Ws);
    for (int i = t; i < 2880; i += 256) {          // 72 rows x 40 float4
        const int row = i / 40, q = i - row * 40;
        const float sc = csm[row * J_U + (q >> 2)];
        const float4 w = Wr4[(size_t)(m0 + row) * 40 + q];
        Ws4[i] = make_float4(w.x * sc, w.y * sc, w.z * sc, w.w * sc);
    }
    for (int i = t; i < 1152; i += 256) {          // 72 rows x 16 float4 (64 b each)
        const int row = i >> 4, col = i & 15;
        const float4 xv = *reinterpret_cast<const float4*>(
            Xt + (size_t)(m0 + row) * B_SZ + bq4 * 64 + col * 4);
        *reinterpret_cast<float4*>(&Xs[row * 64 + col * 4]) = xv;
    }
    __syncthreads();
    // ---- main loop: pure LDS (x b128 conflict-free, w b64 broadcast) ----
    const int bq = t & 15, ng = t >> 4;
    float acc[4][10] = {};
#pragma unroll 4
    for (int m = 0; m < 72; ++m) {
        const float4 cur = *reinterpret_cast<const float4*>(&Xs[m * 64 + bq * 4]);
        const float2* wr = reinterpret_cast<const float2*>(Ws + m * N_DIM + ng * J_U);
        const float xv[4] = {cur.x, cur.y, cur.z, cur.w};
#pragma unroll
        for (int jj = 0; jj < 5; ++jj) {
            const float2 wv = wr[jj];
#pragma unroll
            for (int i = 0; i < 4; ++i) {
                acc[i][2 * jj]     += xv[i] * wv.x;
                acc[i][2 * jj + 1] += xv[i] * wv.y;
            }
        }
    }
    // ---- store split-K partials (plain stores) ----
    float* sp = s_part + (size_t)ch * 40960 + (size_t)(bq4 * 64 + bq * 4) * N_DIM + ng * J_U;
#pragma unroll
    for (int i = 0; i < 4; ++i) {
        float2* p = reinterpret_cast<float2*>(sp + (size_t)i * N_DIM);
#pragma unroll
        for (int jj = 0; jj < 5; ++jj) p[jj] = make_float2(acc[i][2 * jj], acc[i][2 * jj + 1]);
    }
}

// ================= squash: reduce 128 slices, squash over d -> dst =================
__global__ __launch_bounds__(320) void k_squash(const float* __restrict__ s_part,
                                                float* __restrict__ dst) {
    __shared__ float red[320];
    __shared__ float sq[160];
    const int b = blockIdx.x, t = threadIdx.x;
    const int n = t % 160, h = t / 160;
    float s = 0.f;
    const float* p = s_part + (size_t)h * 64 * 40960 + (size_t)b * N_DIM + n;
#pragma unroll 8
    for (int sl = 0; sl < 64; ++sl) s += p[(size_t)sl * 40960];
    red[t] = s;
    __syncthreads();
    if (t < 160) {
        s = red[t] + red[t + 160] + 1e-5f;   // reference adds 1e-5 BEFORE magnitudes
        sq[t] = s * s;
        red[t] = s;
    }
    __syncthreads();
    if (t < 160) {
        const int j0 = t & ~15;
        float mag = 0.f;
#pragma unroll
        for (int d = 0; d < 16; ++d) mag += sq[j0 + d];
        dst[(size_t)b * N_DIM + t] = red[t] * (sqrtf(mag) / (1.f + mag));
    }
}

// ================= gemm2: 144 m-tiles(64) x 4 b-quarters(64 b) = 576 blocks =========
// G-tile[64][160] = sum_{b in quarter} x[b,m]*v[b,n] in regs (coalesced x, 4-deep pf),
// then LDS round-trip fold with Wr (coalesced float4) -> agg_part[bq*8+k][c][j].
__global__ __launch_bounds__(256) void k_gemm2(const float* __restrict__ x,
                                               const float* __restrict__ v,
                                               const float* __restrict__ Wr,
                                               float* __restrict__ agg_part) {
    __shared__ alignas(16) float VG[64 * 164];   // v-panel [64][160] then G-tile [64][164]
    __shared__ float agg[640];                   // 64 c x 10 j
    const int mt = blockIdx.x >> 2, bq = blockIdx.x & 3;
    const int m0 = mt * 64, b0 = bq * 64;
    const int t = threadIdx.x;
    const int tm = t & 15, ng = t >> 4;

    // stage v quarter (packed [64][160])
    float4* Vs4 = reinterpret_cast<float4*>(VG);
    const float4* v4 = reinterpret_cast<const float4*>(v);
    for (int i = t; i < 2560; i += 256) Vs4[i] = v4[(size_t)bq * 2560 + i];
    for (int i = t; i < 640; i += 256) agg[i] = 0.f;
    __syncthreads();

    // main loop over 64 b: x coalesced (256B/wave-instr), v broadcast from LDS
    float acc[4][10] = {};
    const float* xb = x + (size_t)b0 * M_DIM + m0 + tm * 4;
    const float2* Vs2 = reinterpret_cast<const float2*>(VG);
    float4 pf[4];
#pragma unroll
    for (int i = 0; i < 4; ++i) pf[i] = *reinterpret_cast<const float4*>(xb + (size_t)i * M_DIM);
#pragma unroll 4
    for (int b = 0; b < 64; ++b) {
        const int bf = (b + 4 < 64) ? b + 4 : 63;            // clamped prefetch
        const float4 nxt = *reinterpret_cast<const float4*>(xb + (size_t)bf * M_DIM);
        const float4 cur = pf[0];
        pf[0] = pf[1]; pf[1] = pf[2]; pf[2] = pf[3]; pf[3] = nxt;
        const float2* vv = Vs2 + b * 80 + ng * 5;
        const float xv[4] = {cur.x, cur.y, cur.z, cur.w};
#pragma unroll
        for (int jj = 0; jj < 5; ++jj) {
            const float2 w = vv[jj];
#pragma unroll
            for (int i = 0; i < 4; ++i) {
                acc[i][2 * jj]     += xv[i] * w.x;
                acc[i][2 * jj + 1] += xv[i] * w.y;
            }
        }
    }
    __syncthreads();   // all waves done reading v-panel; reuse VG for G-tile
    // scatter acc -> G-tile (row stride 164 floats = 656 B, 16B-aligned rows)
#pragma unroll
    for (int i = 0; i < 4; ++i)
#pragma unroll
        for (int q = 0; q < 10; ++q)
            VG[(tm * 4 + i) * 164 + ng * 10 + q] = acc[i][q];
    __syncthreads();
    // coalesced fold: 64 rows x 40 float4 of Wr ⊙ G, one j per float4
    const float4* Wr4 = reinterpret_cast<const float4*>(Wr);
    for (int idx = t; idx < 2560; idx += 256) {
        const int row = idx / 40, q = idx - row * 40;
        const float4 w = Wr4[(size_t)(m0 + row) * 40 + q];
        const float4 g = *reinterpret_cast<const float4*>(&VG[row * 164 + q * 4]);
        atomicAdd(&agg[row * J_U + (q >> 2)], w.x * g.x + w.y * g.y + w.z * g.z + w.w * g.w);
    }
    __syncthreads();
    const int k = m0 / C_IN, c0 = m0 - k * C_IN;   // 64-tile never crosses a k-slice
    for (int i = t; i < 640; i += 256)
        agg_part[(size_t)(bq * 8 + k) * 11520 + c0 * J_U + i] = agg[i];
}

extern "C" void kernel_launch(void* const* d_in, const int* in_sizes, int n_in,
                              void* d_out, int out_size, void* d_ws, size_t ws_size,
                              hipStream_t stream) {
    const float* x = (const float*)d_in[0];   // (256, 8, 1152) fp32
    const float* W = (const float*)d_in[1];   // (1, 1152, 10, 16, 8) fp32
    float* out = (float*)d_out;               // (256, 10, 16, 1) fp32
    float* ws  = (float*)d_ws;
    float* Xt   = ws + OFF_XT;
    float* Wr   = ws + OFF_WR;
    float* sp   = ws + OFF_SP;
    float* v    = ws + OFF_V;
    float* bij0 = ws + OFF_B0;
    float* bij1 = ws + OFF_B1;
    float* agg  = ws + OFF_AG;
    const float4* Wr4 = (const float4*)Wr;

    k_prep<<<2016, 256, 0, stream>>>(x, W, ws);

    for (int it = 0; it < 4; ++it) {
        const float* bo = (it & 1) ? bij1 : bij0;
        float*       bn = (it & 1) ? bij0 : bij1;
        k_gemm1<<<512, 256, 0, stream>>>(Xt, Wr4, bo, bn, agg, sp, it == 0 ? 1 : 0);
        k_squash<<<256, 320, 0, stream>>>(sp, (it < 3) ? v : out);
        if (it < 3)   // last iteration's agreement is never used
            k_gemm2<<<576, 256, 0, stream>>>(x, v, Wr, agg);
    }
}